// Round 13
// baseline (1595.200 us; speedup 1.0000x reference)
//
#include <hip/hip_runtime.h>
#include <cstdint>

#define HH 384
#define NBINS 256

typedef __attribute__((ext_vector_type(8))) short short8v;
typedef __attribute__((ext_vector_type(16))) float f32x16;
typedef __attribute__((ext_vector_type(4))) unsigned short ushort4v;

__device__ inline float4 ld4(const float* p){ return *(const float4*)p; }

__device__ inline unsigned short bf16_rne(float f){
  unsigned u = __float_as_uint(f);
  unsigned r = u + 0x7FFFu + ((u >> 16) & 1u);
  return (unsigned short)(r >> 16);
}
__device__ inline float bf16_to_f(unsigned short h){
  return __uint_as_float(((unsigned)h) << 16);
}

// ---------------- pos = cumsum(x[...,0]!=0) * mask ----------------
__global__ __launch_bounds__(1024) void pos_kernel(const float* __restrict__ x,
    int* __restrict__ pos, int T)
{
  __shared__ int s[1024];
  int b = blockIdx.x, tid = threadIdx.x;
  int m = 0;
  if (tid < T) m = (x[((size_t)b*T + tid)*HH] != 0.f) ? 1 : 0;
  s[tid] = m;
  __syncthreads();
  for (int off = 1; off < 1024; off <<= 1){
    int add = (tid >= off) ? s[tid-off] : 0;
    __syncthreads();
    s[tid] += add;
    __syncthreads();
  }
  if (tid < T) pos[(size_t)b*T + tid] = s[tid] * m;
}

// ---------------- out = x + alpha * sinusoidal_pe(pos) ----------------
__global__ __launch_bounds__(HH) void add_pe_kernel(const float* __restrict__ x,
    const int* __restrict__ pos, const float* __restrict__ alpha,
    float* __restrict__ out)
{
  int row = blockIdx.x; int i = threadIdx.x;
  int p = pos[row];
  float pe = 0.f;
  if (p != 0){
    int j = (i < HH/2) ? i : i - HH/2;
    float inv = expf((float)j * -0.04822167734018944f); // -ln(10000)/191
    float ang = (float)p * inv;
    pe = (i < HH/2) ? sinf(ang) : cosf(ang);
  }
  out[(size_t)row*HH + i] = x[(size_t)row*HH + i] + alpha[0]*pe;
}

// ---------------- weight transform: w[l][o][i][k] f32 -> B-frag bf16 hi/lo ---
// 32x32x16 B layout: lane l: col n = l&31, k-slot = (l>>5)*8 + j.
// PHASE-MAJOR K-order for K-chunked A staging: phase p = ch/192.
// step s = p*12*K + k*12 + ((ch%192)>>4); within step: half=(ch>>3)&1, jj=ch&7.
// Storage per layer: [hi | lo], each split [s][half(2)][o(384)][jj(8)],
// padded +2 steps so the conv pipeline may overrun harmlessly at the very end.
template<int K>
__global__ __launch_bounds__(256) void wtrans_kernel(const float* __restrict__ w,
    unsigned short* __restrict__ dst, int nlayers)
{
  constexpr int SPL = (24*K + 2) * 6144;   // shorts per split (padded)
  const int per = 384*384;
  int gid = blockIdx.x*256 + threadIdx.x;
  if (gid >= nlayers*per) return;
  int l = gid / per, rem = gid - l*per;
  int o = rem / 384, i = rem - (rem/384)*384;
  unsigned short* whi = dst + (size_t)l*2*SPL;
  unsigned short* wlo = whi + SPL;
  const float* wl = w + (size_t)l*384*384*K;
  int ph = (i >= 192) ? 1 : 0;
  int iloc = i - 192*ph;
  int c = iloc >> 4, half = (iloc >> 3) & 1, jj = iloc & 7;
  #pragma unroll
  for (int k = 0; k < K; ++k){
    float v = wl[((size_t)o*384 + i)*K + k];
    unsigned short hi = bf16_rne(v);
    unsigned short lo = bf16_rne(v - bf16_to_f(hi));
    int s = ph*12*K + k*12 + c;
    size_t d = ((size_t)(s*2 + half)*384 + o)*8 + jj;
    whi[d] = hi; wlo[d] = lo;
  }
}

// ---------------- fused conv1d(same,K)+relu+LN via bf16-split 32x32x16 MFMA --
// r13: TLP. Block = 64 timesteps x 384 o, 512 threads = 8 waves:
// wave wv -> row-group rg=wv>>2 (rows rg*32..+31), o-range nw=wv&3
// (o in [nw*96,+96) as 3 tiles of 32). 9 MFMA/step/wave.
// K-CHUNKED A staging (192 ch/phase, 2 phases): LDS ~58KB -> 2 blocks/CU x
// 8 waves = 16 waves/CU = 4 waves/SIMD (r5-r12 had only 2/SIMD; all pipes
// <50% busy = latency/TLP-bound, so TLP is the last untested axis; r6's
// 8-wave test was confounded by 1-block/CU correlated barriers).
// 3-term split: xh*wh + xh*wl + xl*wh. Counted vmcnt (r12 machinery):
// inline-asm B loads, wait vmcnt(6) keeps next step's 6 in flight.
template<int K>
__global__ __launch_bounds__(512) void conv_mfma_kernel(
    const float* __restrict__ in, const unsigned short* __restrict__ whi,
    const unsigned short* __restrict__ wlo, const float* __restrict__ bias,
    const float* __restrict__ g, const float* __restrict__ be,
    float* __restrict__ out, int T)
{
  constexpr int MT  = 64;
  constexpr int P   = (K-1)/2;
  constexpr int RT  = MT + K - 1;
  constexpr int RA  = RT + 2;        // +2 rows: prefetch overrun pad
  constexpr int SPH = 12*K;          // steps per phase (60 / 36)
  constexpr int LDPc = 200;          // 192 + 8 pad: 400B row stride
  __shared__ unsigned short xs_hi[RA*LDPc];
  __shared__ unsigned short xs_lo[RA*LDPc];
  __shared__ float ps[8][32], pq[8][32];

  int ntile = T / MT;
  int b  = blockIdx.x / ntile;
  int t0 = (blockIdx.x % ntile) * MT;
  int tid = threadIdx.x;
  const float* inb = in + (size_t)b*T*HH;

  int wv = tid >> 6, ln = tid & 63;
  int l31 = ln & 31, hl = ln >> 5;
  int nw = wv & 3, rg = wv >> 2;
  int o0 = nw * 96;

  f32x16 acc[3];
  #pragma unroll
  for (int nt = 0; nt < 3; ++nt){
    float bv = bias[o0 + nt*32 + l31];
    #pragma unroll
    for (int r = 0; r < 16; ++r) acc[nt][r] = bv;
  }

#define GLOAD(dst, p) \
  asm volatile("global_load_dwordx4 %0, %1, off" : "=v"(dst) : "v"(p))

  for (int phse = 0; phse < 2; ++phse){
    if (phse) __syncthreads();   // all waves done reading previous A phase

    // ---- stage channels [phse*192, phse*192+192) for RT rows, bf16 hi/lo ----
    for (int e4 = tid; e4 < RT*48; e4 += 512){
      int r = e4 / 48, c4 = (e4 - r*48)*4;
      int t = t0 + r - P;
      float4 v = (t >= 0 && t < T) ? ld4(&inb[(size_t)t*HH + phse*192 + c4])
                                   : make_float4(0.f,0.f,0.f,0.f);
      float va[4] = {v.x, v.y, v.z, v.w};
      ushort4v h, l;
      #pragma unroll
      for (int q = 0; q < 4; ++q){
        unsigned short hq = bf16_rne(va[q]);
        h[q] = hq;
        l[q] = bf16_rne(va[q] - bf16_to_f(hq));
      }
      *(ushort4v*)&xs_hi[r*LDPc + c4] = h;
      *(ushort4v*)&xs_lo[r*LDPc + c4] = l;
    }
    __syncthreads();

    const unsigned short* bhp = whi + (size_t)phse*SPH*6144
                                    + ((size_t)hl*384 + o0 + l31)*8;
    const unsigned short* blp = wlo + (size_t)phse*SPH*6144
                                    + ((size_t)hl*384 + o0 + l31)*8;
    int aoff = (rg*32 + l31)*LDPc + hl*8;
    int cc = 0;

    short8v B0h[3], B0l[3], B1h[3], B1l[3];
    short8v A0h, A0l, A1h, A1l;

#define ADVB do{ bhp += 6144; blp += 6144; }while(0)
#define ADVA do{ aoff += 16;                                                 \
                 if (++cc == 12){ cc = 0; aoff += LDPc - 192; } }while(0)

    // prologue: B set 0 <- step 0 (6 loads in flight); A set 0 <- step 0
    GLOAD(B0h[0], bhp);        GLOAD(B0h[1], bhp + 256); GLOAD(B0h[2], bhp + 512);
    GLOAD(B0l[0], blp);        GLOAD(B0l[1], blp + 256); GLOAD(B0l[2], blp + 512);
    ADVB;
    A0h = *(const short8v*)&xs_hi[aoff];
    A0l = *(const short8v*)&xs_lo[aoff];
    ADVA;

#define STEP(CBh,CBl,CAh,CAl, NBh,NBl,NAh,NAl) do{                           \
    GLOAD(NBh[0], bhp);       GLOAD(NBh[1], bhp + 256);                      \
    GLOAD(NBh[2], bhp + 512); GLOAD(NBl[0], blp);                            \
    GLOAD(NBl[1], blp + 256); GLOAD(NBl[2], blp + 512);                      \
    ADVB;                                                                    \
    NAh = *(const short8v*)&xs_hi[aoff];                                     \
    NAl = *(const short8v*)&xs_lo[aoff];                                     \
    ADVA;                                                                    \
    asm volatile("s_waitcnt vmcnt(6)");                                      \
    __builtin_amdgcn_sched_barrier(0);                                       \
    __builtin_amdgcn_s_setprio(1);                                           \
    _Pragma("unroll")                                                        \
    for (int nt = 0; nt < 3; ++nt)                                           \
      acc[nt] = __builtin_amdgcn_mfma_f32_32x32x16_bf16(CAh, CBh[nt], acc[nt], 0,0,0); \
    _Pragma("unroll")                                                        \
    for (int nt = 0; nt < 3; ++nt)                                           \
      acc[nt] = __builtin_amdgcn_mfma_f32_32x32x16_bf16(CAh, CBl[nt], acc[nt], 0,0,0); \
    _Pragma("unroll")                                                        \
    for (int nt = 0; nt < 3; ++nt)                                           \
      acc[nt] = __builtin_amdgcn_mfma_f32_32x32x16_bf16(CAl, CBh[nt], acc[nt], 0,0,0); \
    __builtin_amdgcn_s_setprio(0);                                           \
  } while(0)

    for (int s = 0; s < SPH; s += 2){
      STEP(B0h,B0l,A0h,A0l, B1h,B1l,A1h,A1l);
      STEP(B1h,B1l,A1h,A1l, B0h,B0l,A0h,A0l);
    }
#undef STEP
#undef ADVB
#undef ADVA

    // drain the (dead, pad-targeted) in-flight loads before barrier/epilogue
    asm volatile("s_waitcnt vmcnt(0)");
    __builtin_amdgcn_sched_barrier(0);
  }
#undef GLOAD

  // ---- relu + LN over channels ----
  // D layout (32x32): col o = o0+nt*32+l31; local row t = (r&3)+8*(r>>2)+4*hl
  float gv[3], bev[3];
  #pragma unroll
  for (int nt = 0; nt < 3; ++nt){
    gv[nt]  = g[o0 + nt*32 + l31];
    bev[nt] = be[o0 + nt*32 + l31];
  }

  #pragma unroll
  for (int r = 0; r < 16; ++r){
    float s1 = 0.f, s2 = 0.f;
    #pragma unroll
    for (int nt = 0; nt < 3; ++nt){
      float v = fmaxf(acc[nt][r], 0.f);
      acc[nt][r] = v;
      s1 += v; s2 += v*v;
    }
    s1 += __shfl_xor(s1, 1);  s2 += __shfl_xor(s2, 1);
    s1 += __shfl_xor(s1, 2);  s2 += __shfl_xor(s2, 2);
    s1 += __shfl_xor(s1, 4);  s2 += __shfl_xor(s2, 4);
    s1 += __shfl_xor(s1, 8);  s2 += __shfl_xor(s2, 8);
    s1 += __shfl_xor(s1, 16); s2 += __shfl_xor(s2, 16);
    if (l31 == 0){
      int t = (r&3) + 8*(r>>2) + 4*hl;
      ps[wv][t] = s1; pq[wv][t] = s2;
    }
  }
  __syncthreads();

  #pragma unroll
  for (int r = 0; r < 16; ++r){
    int t = (r&3) + 8*(r>>2) + 4*hl;
    float s1 = ps[rg*4+0][t] + ps[rg*4+1][t] + ps[rg*4+2][t] + ps[rg*4+3][t];
    float s2 = pq[rg*4+0][t] + pq[rg*4+1][t] + pq[rg*4+2][t] + pq[rg*4+3][t];
    float mn  = s1 * (1.f/HH);
    float var = fmaxf(s2 * (1.f/HH) - mn*mn, 0.f);
    float rr  = rsqrtf(var + 1e-5f);
    float* orow = out + ((size_t)b*T + t0 + rg*32 + t)*HH;
    #pragma unroll
    for (int nt = 0; nt < 3; ++nt)
      orow[o0 + nt*32 + l31] = (acc[nt][r] - mn)*rr*gv[nt] + bev[nt];
  }
}

// ---------------- pred = h @ lw + lb ; idx = searchsorted(bins, pred, 'left') ----
__global__ __launch_bounds__(256) void proj_var_kernel(const float* __restrict__ h,
    const float* __restrict__ lw, const float* __restrict__ lb,
    const float* __restrict__ bins, float* __restrict__ pred,
    int* __restrict__ idx, int nrows)
{
  int lane = threadIdx.x & 63, wid = threadIdx.x >> 6;
  int wave = blockIdx.x*4 + wid, nw = gridDim.x*4;
  float lwr[6];
  #pragma unroll
  for (int j = 0; j < 6; ++j) lwr[j] = lw[lane + 64*j];
  float lbv = lb[0];
  for (int row = wave; row < nrows; row += nw){
    const float* hr = h + (size_t)row*HH;
    float s = 0.f;
    #pragma unroll
    for (int j = 0; j < 6; ++j) s = fmaf(hr[lane + 64*j], lwr[j], s);
    #pragma unroll
    for (int off = 32; off; off >>= 1) s += __shfl_xor(s, off);
    if (lane == 0){
      float v = s + lbv;
      pred[row] = v;
      int lo = 0, hi = NBINS - 1;
      while (lo < hi){ int mid = (lo + hi) >> 1; if (bins[mid] < v) lo = mid + 1; else hi = mid; }
      idx[row] = lo;
    }
  }
}

// ---------------- log_d, dur (float), dur (int) ----------------
__global__ __launch_bounds__(256) void proj_dur_kernel(const float* __restrict__ h,
    const float* __restrict__ lw, const float* __restrict__ lb,
    const unsigned char* __restrict__ mask, float* __restrict__ logd,
    float* __restrict__ durf, int* __restrict__ duri, int nrows)
{
  int lane = threadIdx.x & 63, wid = threadIdx.x >> 6;
  int wave = blockIdx.x*4 + wid, nw = gridDim.x*4;
  float lwr[6];
  #pragma unroll
  for (int j = 0; j < 6; ++j) lwr[j] = lw[lane + 64*j];
  float lbv = lb[0];
  for (int row = wave; row < nrows; row += nw){
    const float* hr = h + (size_t)row*HH;
    float s = 0.f;
    #pragma unroll
    for (int j = 0; j < 6; ++j) s = fmaf(hr[lane + 64*j], lwr[j], s);
    #pragma unroll
    for (int off = 32; off; off >>= 1) s += __shfl_xor(s, off);
    if (lane == 0){
      float v = s + lbv;
      if (mask[row]) v = 0.f;
      logd[row] = v;
      float d = fmaxf(rintf(expf(v) - 1.f), 0.f);
      durf[row] = d;
      duri[row] = (int)d;
    }
  }
}

// ---------------- per-batch inclusive cumsum of dur, mel_len ----------------
__global__ __launch_bounds__(1024) void cumsum_kernel(const int* __restrict__ duri,
    int* __restrict__ cum, float* __restrict__ mel, int T, int ML)
{
  __shared__ int s[1024];
  int b = blockIdx.x, tid = threadIdx.x;
  s[tid] = (tid < T) ? duri[(size_t)b*T + tid] : 0;
  __syncthreads();
  for (int off = 1; off < 1024; off <<= 1){
    int add = (tid >= off) ? s[tid-off] : 0;
    __syncthreads();
    s[tid] += add;
    __syncthreads();
  }
  if (tid < T) cum[(size_t)b*T + tid] = s[tid];
  if (tid == T-1) mel[b] = (float)min(s[tid], ML);
}

// ---------------- x_adapt = x + pitch_table[ip] + energy_table[ie] ----------------
__global__ __launch_bounds__(256) void xadapt_kernel(const float* __restrict__ x,
    const int* __restrict__ ip, const int* __restrict__ ie,
    const float* __restrict__ pt, const float* __restrict__ et,
    float* __restrict__ xa, int nrows)
{
  int gid = blockIdx.x*256 + threadIdx.x;
  int n4 = nrows * (HH/4);
  if (gid >= n4) return;
  int row = gid / (HH/4);
  int c = gid - row*(HH/4);
  float4 xv = ((const float4*)x)[gid];
  const float4* pr = (const float4*)(pt + (size_t)ip[row]*HH);
  const float4* er = (const float4*)(et + (size_t)ie[row]*HH);
  float4 pv = pr[c], ev = er[c];
  ((float4*)xa)[gid] = make_float4(xv.x+pv.x+ev.x, xv.y+pv.y+ev.y,
                                   xv.z+pv.z+ev.z, xv.w+pv.w+ev.w);
}

// ---------------- length regulate: gather + zero-fill ----------------
__global__ __launch_bounds__(256) void lr_kernel(const float* __restrict__ xa,
    const int* __restrict__ cum, float* __restrict__ out, int T, int ML)
{
  constexpr int FR = 32;
  __shared__ int scum[1024];
  __shared__ int sidx[FR];
  __shared__ int svalid[FR];
  int b  = blockIdx.y;
  int f0 = blockIdx.x * FR;
  for (int i = threadIdx.x; i < T; i += 256) scum[i] = cum[(size_t)b*T + i];
  __syncthreads();
  int total = scum[T-1];
  if (threadIdx.x < FR){
    int f = f0 + threadIdx.x;
    int lo = 0, hi = T;
    while (lo < hi){ int mid = (lo + hi) >> 1; if (scum[mid] <= f) lo = mid + 1; else hi = mid; }
    sidx[threadIdx.x] = min(lo, T-1);
    svalid[threadIdx.x] = (f < total) ? 1 : 0;
  }
  __syncthreads();
  #pragma unroll
  for (int it = 0; it < FR*(HH/4)/256; ++it){
    int item = it*256 + threadIdx.x;
    int fl = item / (HH/4);
    int c  = item - fl*(HH/4);
    int f  = f0 + fl;
    if (f >= ML) continue;
    float4 v = make_float4(0.f,0.f,0.f,0.f);
    if (svalid[fl]) v = ((const float4*)(xa + ((size_t)b*T + sidx[fl])*HH))[c];
    ((float4*)(out + ((size_t)b*ML + f)*HH))[c] = v;
  }
}

extern "C" void kernel_launch(void* const* d_in, const int* in_sizes, int n_in,
                              void* d_out, int out_size, void* d_ws, size_t ws_size,
                              hipStream_t stream)
{
  const float* x        = (const float*)d_in[0];
  const unsigned char* src_mask = (const unsigned char*)d_in[2];
  const float* dp_w1 = (const float*)d_in[4];
  const float* dp_b1 = (const float*)d_in[5];
  const float* dp_g1 = (const float*)d_in[6];
  const float* dp_be1= (const float*)d_in[7];
  const float* dp_w2 = (const float*)d_in[8];
  const float* dp_b2 = (const float*)d_in[9];
  const float* dp_g2 = (const float*)d_in[10];
  const float* dp_be2= (const float*)d_in[11];
  const float* dp_lw = (const float*)d_in[12];
  const float* dp_lb = (const float*)d_in[13];
  const float* pp_cw = (const float*)d_in[14];
  const float* pp_cb = (const float*)d_in[15];
  const float* pp_g  = (const float*)d_in[16];
  const float* pp_b  = (const float*)d_in[17];
  const float* pp_lw = (const float*)d_in[18];
  const float* pp_lb = (const float*)d_in[19];
  const float* pp_alpha = (const float*)d_in[20];
  const float* ep_cw = (const float*)d_in[21];
  const float* ep_cb = (const float*)d_in[22];
  const float* ep_g  = (const float*)d_in[23];
  const float* ep_b  = (const float*)d_in[24];
  const float* ep_lw = (const float*)d_in[25];
  const float* ep_lb = (const float*)d_in[26];
  const float* ep_alpha = (const float*)d_in[27];
  const float* pbins = (const float*)d_in[28];
  const float* ebins = (const float*)d_in[29];
  const float* ptab  = (const float*)d_in[30];
  const float* etab  = (const float*)d_in[31];

  int B = in_sizes[1];
  int T = in_sizes[0] / (B*HH);
  int ML = (int)(((long long)out_size - B - 4LL*B*T) / ((long long)B*HH));
  size_t rows = (size_t)B*T;

  float* bufA = (float*)d_ws;
  float* bufB = bufA + rows*HH;
  int* pos    = (int*)(bufB + rows*HH);
  int* idx_p  = pos + rows;
  int* idx_e  = idx_p + rows;
  int* dur_i  = idx_e + rows;
  int* cum    = dur_i + rows;

  float* out0    = (float*)d_out;
  float* logd    = out0 + (size_t)B*ML*HH;
  float* durf    = logd + rows;
  float* pitchp  = durf + rows;
  float* energyp = pitchp + rows;
  float* mel     = energyp + rows;

  // Transformed-weight scratch lives in the out0 gather region (201 MB);
  // lr_kernel fully overwrites it at the end of every call. ~25 MB used.
  const size_t SPL5 = (size_t)(24*5 + 2)*6144;  // shorts per split, k=5
  const size_t SPL3 = (size_t)(24*3 + 2)*6144;  // shorts per split, k=3
  unsigned short* wsc    = (unsigned short*)d_out;
  unsigned short* pitchW = wsc;
  unsigned short* enerW  = pitchW + 5*2*SPL5;
  unsigned short* durW1  = enerW  + 2*2*SPL5;
  unsigned short* durW2  = durW1  + 2*SPL3;

  const int per = 384*384;
  wtrans_kernel<5><<<(5*per + 255)/256, 256, 0, stream>>>(pp_cw, pitchW, 5);
  wtrans_kernel<5><<<(2*per + 255)/256, 256, 0, stream>>>(ep_cw, enerW, 2);
  wtrans_kernel<3><<<(per + 255)/256, 256, 0, stream>>>(dp_w1, durW1, 1);
  wtrans_kernel<3><<<(per + 255)/256, 256, 0, stream>>>(dp_w2, durW2, 1);

  int conv_grid = B * (T / 64);

  pos_kernel<<<B, 1024, 0, stream>>>(x, pos, T);

  // ---- pitch predictor: 5 conv layers (k=5, MFMA) ----
  add_pe_kernel<<<(int)rows, HH, 0, stream>>>(x, pos, pp_alpha, bufA);
  {
    float* src = bufA; float* dst = bufB;
    for (int l = 0; l < 5; ++l){
      unsigned short* whi = pitchW + (size_t)l*2*SPL5;
      conv_mfma_kernel<5><<<conv_grid, 512, 0, stream>>>(src, whi, whi + SPL5,
          pp_cb + (size_t)l*HH, pp_g + (size_t)l*HH, pp_b + (size_t)l*HH, dst, T);
      float* t2 = dst; dst = src; src = t2;
    }
    proj_var_kernel<<<256, 256, 0, stream>>>(src, pp_lw, pp_lb, pbins,
                                             pitchp, idx_p, (int)rows);
  }

  // ---- energy predictor: 2 conv layers (k=5, MFMA) ----
  add_pe_kernel<<<(int)rows, HH, 0, stream>>>(x, pos, ep_alpha, bufA);
  {
    float* src = bufA; float* dst = bufB;
    for (int l = 0; l < 2; ++l){
      unsigned short* whi = enerW + (size_t)l*2*SPL5;
      conv_mfma_kernel<5><<<conv_grid, 512, 0, stream>>>(src, whi, whi + SPL5,
          ep_cb + (size_t)l*HH, ep_g + (size_t)l*HH, ep_b + (size_t)l*HH, dst, T);
      float* t2 = dst; dst = src; src = t2;
    }
    proj_var_kernel<<<256, 256, 0, stream>>>(src, ep_lw, ep_lb, ebins,
                                             energyp, idx_e, (int)rows);
  }

  // ---- duration predictor: 2 conv layers (k=3, MFMA) ----
  conv_mfma_kernel<3><<<conv_grid, 512, 0, stream>>>(x, durW1, durW1 + SPL3,
      dp_b1, dp_g1, dp_be1, bufB, T);
  conv_mfma_kernel<3><<<conv_grid, 512, 0, stream>>>(bufB, durW2, durW2 + SPL3,
      dp_b2, dp_g2, dp_be2, bufA, T);
  proj_dur_kernel<<<256, 256, 0, stream>>>(bufA, dp_lw, dp_lb, src_mask,
                                           logd, durf, dur_i, (int)rows);

  cumsum_kernel<<<B, 1024, 0, stream>>>(dur_i, cum, mel, T, ML);

  xadapt_kernel<<<(int)((rows*(HH/4) + 255)/256), 256, 0, stream>>>(
      x, idx_p, idx_e, ptab, etab, bufB, (int)rows);

  lr_kernel<<<dim3(ML/32, B), 256, 0, stream>>>(bufB, cum, out0, T, ML);
}

// Round 14
// 1371.191 us; speedup vs baseline: 1.1634x; 1.1634x over previous
//
#include <hip/hip_runtime.h>
#include <cstdint>

#define HH 384
#define NBINS 256

typedef __attribute__((ext_vector_type(8))) short short8v;
typedef __attribute__((ext_vector_type(16))) float f32x16;
typedef __attribute__((ext_vector_type(4))) unsigned short ushort4v;

__device__ inline float4 ld4(const float* p){ return *(const float4*)p; }

__device__ inline unsigned short bf16_rne(float f){
  unsigned u = __float_as_uint(f);
  unsigned r = u + 0x7FFFu + ((u >> 16) & 1u);
  return (unsigned short)(r >> 16);
}
__device__ inline float bf16_to_f(unsigned short h){
  return __uint_as_float(((unsigned)h) << 16);
}

// ---------------- pos = cumsum(x[...,0]!=0) * mask ----------------
__global__ __launch_bounds__(1024) void pos_kernel(const float* __restrict__ x,
    int* __restrict__ pos, int T)
{
  __shared__ int s[1024];
  int b = blockIdx.x, tid = threadIdx.x;
  int m = 0;
  if (tid < T) m = (x[((size_t)b*T + tid)*HH] != 0.f) ? 1 : 0;
  s[tid] = m;
  __syncthreads();
  for (int off = 1; off < 1024; off <<= 1){
    int add = (tid >= off) ? s[tid-off] : 0;
    __syncthreads();
    s[tid] += add;
    __syncthreads();
  }
  if (tid < T) pos[(size_t)b*T + tid] = s[tid] * m;
}

// ---------------- weight transform: w[l][o][i][k] f32 -> B-frag bf16 hi/lo ---
// 32x32x16 B layout: lane l: col n = l&31, k-slot = (l>>5)*8 + j.
// PHASE-MAJOR K-order for K-chunked A staging: phase p = ch/192.
// step s = p*12*K + k*12 + ((ch%192)>>4); within step: half=(ch>>3)&1, jj=ch&7.
// Storage per layer: [hi | lo], each split [s][half(2)][o(384)][jj(8)],
// padded +2 steps so the conv pipeline may overrun harmlessly at the very end.
template<int K>
__global__ __launch_bounds__(256) void wtrans_kernel(const float* __restrict__ w,
    unsigned short* __restrict__ dst, int nlayers)
{
  constexpr int SPL = (24*K + 2) * 6144;   // shorts per split (padded)
  const int per = 384*384;
  int gid = blockIdx.x*256 + threadIdx.x;
  if (gid >= nlayers*per) return;
  int l = gid / per, rem = gid - l*per;
  int o = rem / 384, i = rem - (rem/384)*384;
  unsigned short* whi = dst + (size_t)l*2*SPL;
  unsigned short* wlo = whi + SPL;
  const float* wl = w + (size_t)l*384*384*K;
  int ph = (i >= 192) ? 1 : 0;
  int iloc = i - 192*ph;
  int c = iloc >> 4, half = (iloc >> 3) & 1, jj = iloc & 7;
  #pragma unroll
  for (int k = 0; k < K; ++k){
    float v = wl[((size_t)o*384 + i)*K + k];
    unsigned short hi = bf16_rne(v);
    unsigned short lo = bf16_rne(v - bf16_to_f(hi));
    int s = ph*12*K + k*12 + c;
    size_t d = ((size_t)(s*2 + half)*384 + o)*8 + jj;
    whi[d] = hi; wlo[d] = lo;
  }
}

// ---------------- fused conv1d(same,K)+relu+LN via bf16-split 32x32x16 MFMA --
// r14: conv main loop FROZEN at r12's best config (M=64, 4 waves, K-chunked
// A staging, counted vmcnt(6), 154us, ~935 TF raw = plain-HIP structural
// ceiling; r5-r13 probes of traffic/TLP/depth/schedule all null). This round
// fuses the surrounding elementwise work via MODE:
//   MODE 0: plain conv (+write)
//   MODE 1: staging adds alpha*sinusoidal_pe(pos)  [replaces add_pe_kernel]
//   MODE 2: epilogue = proj + searchsorted, NO output write [replaces proj_var]
//   MODE 3: epilogue = proj + mask/exp/round (duration), NO write
template<int K, int MODE>
__global__ __launch_bounds__(256) void conv_mfma_kernel(
    const float* __restrict__ in, const unsigned short* __restrict__ whi,
    const unsigned short* __restrict__ wlo, const float* __restrict__ bias,
    const float* __restrict__ g, const float* __restrict__ be,
    float* __restrict__ out, int T,
    const int* __restrict__ posp, const float* __restrict__ alpha,
    const float* __restrict__ lw, const float* __restrict__ lb,
    const float* __restrict__ bins, float* __restrict__ pred,
    int* __restrict__ idx,
    const unsigned char* __restrict__ mask, float* __restrict__ logd,
    float* __restrict__ durf, int* __restrict__ duri)
{
  constexpr int MT  = 64;
  constexpr int P   = (K-1)/2;
  constexpr int RT  = MT + K - 1;
  constexpr int RA  = RT + 2;        // +2 rows: prefetch overrun pad
  constexpr int SPH = 12*K;          // steps per phase (60 / 36)
  constexpr int LDPc = 200;          // 192 + 8 pad: 400B row stride
  __shared__ unsigned short xs_hi[RA*LDPc];
  __shared__ unsigned short xs_lo[RA*LDPc];
  __shared__ float ps[4][64], pq[4][64];
  __shared__ float psP[4][64];       // MODE>=2 proj partials
  __shared__ float sinv[192];        // MODE==1 inv-freq table

  int ntile = T / MT;
  int b  = blockIdx.x / ntile;
  int t0 = (blockIdx.x % ntile) * MT;
  int tid = threadIdx.x;
  const float* inb = in + (size_t)b*T*HH;

  int wv = tid >> 6, ln = tid & 63;
  int l31 = ln & 31, hl = ln >> 5;
  int o0 = wv * 96;

  float al = 0.f;
  if constexpr (MODE == 1){
    al = alpha[0];
    if (tid < 192) sinv[tid] = expf((float)tid * -0.04822167734018944f);
    __syncthreads();
  }

  f32x16 acc0[3], acc1[3];
  #pragma unroll
  for (int nt = 0; nt < 3; ++nt){
    float bv = bias[o0 + nt*32 + l31];
    #pragma unroll
    for (int r = 0; r < 16; ++r){ acc0[nt][r] = bv; acc1[nt][r] = bv; }
  }

#define GLOAD(dst, p) \
  asm volatile("global_load_dwordx4 %0, %1, off" : "=v"(dst) : "v"(p))

  for (int phse = 0; phse < 2; ++phse){
    if (phse) __syncthreads();   // all waves done reading previous A phase

    // ---- stage channels [phse*192, phse*192+192) for RT rows, bf16 hi/lo ----
    for (int e4 = tid; e4 < RT*48; e4 += 256){
      int r = e4 / 48, c4 = (e4 - r*48)*4;
      int t = t0 + r - P;
      float4 v = (t >= 0 && t < T) ? ld4(&inb[(size_t)t*HH + phse*192 + c4])
                                   : make_float4(0.f,0.f,0.f,0.f);
      float va[4] = {v.x, v.y, v.z, v.w};
      if constexpr (MODE == 1){
        if (t >= 0 && t < T){
          int p = posp[(size_t)b*T + t];
          if (p){
            #pragma unroll
            for (int q = 0; q < 4; ++q){
              float ang = (float)p * sinv[c4 + q];
              va[q] += al * (phse == 0 ? sinf(ang) : cosf(ang));
            }
          }
        }
      }
      ushort4v h, l;
      #pragma unroll
      for (int q = 0; q < 4; ++q){
        unsigned short hq = bf16_rne(va[q]);
        h[q] = hq;
        l[q] = bf16_rne(va[q] - bf16_to_f(hq));
      }
      *(ushort4v*)&xs_hi[r*LDPc + c4] = h;
      *(ushort4v*)&xs_lo[r*LDPc + c4] = l;
    }
    __syncthreads();

    const unsigned short* bhp = whi + (size_t)phse*SPH*6144
                                    + ((size_t)hl*384 + o0 + l31)*8;
    const unsigned short* blp = wlo + (size_t)phse*SPH*6144
                                    + ((size_t)hl*384 + o0 + l31)*8;
    int aoff0 = l31*LDPc + hl*8;          // row-group 0: rows 0..31
    int aoff1 = (32 + l31)*LDPc + hl*8;   // row-group 1: rows 32..63
    int cc = 0;

    short8v B0h[3], B0l[3], B1h[3], B1l[3];
    short8v A00h, A00l, A01h, A01l;   // A set 0: rg0, rg1
    short8v A10h, A10l, A11h, A11l;   // A set 1

#define ADVB do{ bhp += 6144; blp += 6144; }while(0)
#define ADVA do{ aoff0 += 16; aoff1 += 16;                                   \
                 if (++cc == 12){ cc = 0; aoff0 += LDPc - 192;               \
                                  aoff1 += LDPc - 192; } }while(0)

    // prologue: B set 0 <- step 0 (6 loads in flight); A set 0 <- step 0
    GLOAD(B0h[0], bhp);        GLOAD(B0h[1], bhp + 256); GLOAD(B0h[2], bhp + 512);
    GLOAD(B0l[0], blp);        GLOAD(B0l[1], blp + 256); GLOAD(B0l[2], blp + 512);
    ADVB;
    A00h = *(const short8v*)&xs_hi[aoff0];
    A00l = *(const short8v*)&xs_lo[aoff0];
    A01h = *(const short8v*)&xs_hi[aoff1];
    A01l = *(const short8v*)&xs_lo[aoff1];
    ADVA;

#define STEP(CBh,CBl, CA0h,CA0l,CA1h,CA1l, NBh,NBl, NA0h,NA0l,NA1h,NA1l) do{ \
    GLOAD(NBh[0], bhp);       GLOAD(NBh[1], bhp + 256);                      \
    GLOAD(NBh[2], bhp + 512); GLOAD(NBl[0], blp);                            \
    GLOAD(NBl[1], blp + 256); GLOAD(NBl[2], blp + 512);                      \
    ADVB;                                                                    \
    NA0h = *(const short8v*)&xs_hi[aoff0];                                   \
    NA0l = *(const short8v*)&xs_lo[aoff0];                                   \
    NA1h = *(const short8v*)&xs_hi[aoff1];                                   \
    NA1l = *(const short8v*)&xs_lo[aoff1];                                   \
    ADVA;                                                                    \
    asm volatile("s_waitcnt vmcnt(6)");                                      \
    __builtin_amdgcn_sched_barrier(0);                                       \
    __builtin_amdgcn_s_setprio(1);                                           \
    _Pragma("unroll")                                                        \
    for (int nt = 0; nt < 3; ++nt){                                          \
      acc0[nt] = __builtin_amdgcn_mfma_f32_32x32x16_bf16(CA0h, CBh[nt], acc0[nt], 0,0,0); \
      acc1[nt] = __builtin_amdgcn_mfma_f32_32x32x16_bf16(CA1h, CBh[nt], acc1[nt], 0,0,0); \
    }                                                                        \
    _Pragma("unroll")                                                        \
    for (int nt = 0; nt < 3; ++nt){                                          \
      acc0[nt] = __builtin_amdgcn_mfma_f32_32x32x16_bf16(CA0h, CBl[nt], acc0[nt], 0,0,0); \
      acc1[nt] = __builtin_amdgcn_mfma_f32_32x32x16_bf16(CA1h, CBl[nt], acc1[nt], 0,0,0); \
    }                                                                        \
    _Pragma("unroll")                                                        \
    for (int nt = 0; nt < 3; ++nt){                                          \
      acc0[nt] = __builtin_amdgcn_mfma_f32_32x32x16_bf16(CA0l, CBh[nt], acc0[nt], 0,0,0); \
      acc1[nt] = __builtin_amdgcn_mfma_f32_32x32x16_bf16(CA1l, CBh[nt], acc1[nt], 0,0,0); \
    }                                                                        \
    __builtin_amdgcn_s_setprio(0);                                           \
  } while(0)

    for (int s = 0; s < SPH; s += 2){
      STEP(B0h,B0l, A00h,A00l,A01h,A01l, B1h,B1l, A10h,A10l,A11h,A11l);
      STEP(B1h,B1l, A10h,A10l,A11h,A11l, B0h,B0l, A00h,A00l,A01h,A01l);
    }
#undef STEP
#undef ADVB
#undef ADVA

    // drain the (dead, pad-targeted) in-flight loads before barrier/epilogue
    asm volatile("s_waitcnt vmcnt(0)");
    __builtin_amdgcn_sched_barrier(0);
  }
#undef GLOAD

  // ---- relu + LN stats over channels ----
  // D layout (32x32): col o = o0+nt*32+l31; local row = (r&3)+8*(r>>2)+4*hl
  float gv[3], bev[3];
  #pragma unroll
  for (int nt = 0; nt < 3; ++nt){
    gv[nt]  = g[o0 + nt*32 + l31];
    bev[nt] = be[o0 + nt*32 + l31];
  }

  #pragma unroll
  for (int rg = 0; rg < 2; ++rg){
    #pragma unroll
    for (int r = 0; r < 16; ++r){
      float s1 = 0.f, s2 = 0.f;
      #pragma unroll
      for (int nt = 0; nt < 3; ++nt){
        float v = fmaxf(rg ? acc1[nt][r] : acc0[nt][r], 0.f);
        if (rg) acc1[nt][r] = v; else acc0[nt][r] = v;
        s1 += v; s2 += v*v;
      }
      s1 += __shfl_xor(s1, 1);  s2 += __shfl_xor(s2, 1);
      s1 += __shfl_xor(s1, 2);  s2 += __shfl_xor(s2, 2);
      s1 += __shfl_xor(s1, 4);  s2 += __shfl_xor(s2, 4);
      s1 += __shfl_xor(s1, 8);  s2 += __shfl_xor(s2, 8);
      s1 += __shfl_xor(s1, 16); s2 += __shfl_xor(s2, 16);
      if (l31 == 0){
        int t = rg*32 + (r&3) + 8*(r>>2) + 4*hl;
        ps[wv][t] = s1; pq[wv][t] = s2;
      }
    }
  }
  __syncthreads();

  if constexpr (MODE <= 1){
    #pragma unroll
    for (int rg = 0; rg < 2; ++rg){
      #pragma unroll
      for (int r = 0; r < 16; ++r){
        int t = rg*32 + (r&3) + 8*(r>>2) + 4*hl;
        float s1 = ps[0][t] + ps[1][t] + ps[2][t] + ps[3][t];
        float s2 = pq[0][t] + pq[1][t] + pq[2][t] + pq[3][t];
        float mn  = s1 * (1.f/HH);
        float var = fmaxf(s2 * (1.f/HH) - mn*mn, 0.f);
        float rr  = rsqrtf(var + 1e-5f);
        float* orow = out + ((size_t)b*T + t0 + t)*HH;
        #pragma unroll
        for (int nt = 0; nt < 3; ++nt){
          float v = rg ? acc1[nt][r] : acc0[nt][r];
          orow[o0 + nt*32 + l31] = (v - mn)*rr*gv[nt] + bev[nt];
        }
      }
    }
  } else {
    // ---- fused projection epilogue (no output write) ----
    float lwv[3];
    #pragma unroll
    for (int nt = 0; nt < 3; ++nt) lwv[nt] = lw[o0 + nt*32 + l31];
    #pragma unroll
    for (int rg = 0; rg < 2; ++rg){
      #pragma unroll
      for (int r = 0; r < 16; ++r){
        int t = rg*32 + (r&3) + 8*(r>>2) + 4*hl;
        float s1 = ps[0][t] + ps[1][t] + ps[2][t] + ps[3][t];
        float s2 = pq[0][t] + pq[1][t] + pq[2][t] + pq[3][t];
        float mn  = s1 * (1.f/HH);
        float var = fmaxf(s2 * (1.f/HH) - mn*mn, 0.f);
        float rr  = rsqrtf(var + 1e-5f);
        float pv = 0.f;
        #pragma unroll
        for (int nt = 0; nt < 3; ++nt){
          float v = rg ? acc1[nt][r] : acc0[nt][r];
          pv += ((v - mn)*rr*gv[nt] + bev[nt]) * lwv[nt];
        }
        pv += __shfl_xor(pv, 1);  pv += __shfl_xor(pv, 2);
        pv += __shfl_xor(pv, 4);  pv += __shfl_xor(pv, 8);
        pv += __shfl_xor(pv, 16);
        if (l31 == 0) psP[wv][t] = pv;
      }
    }
    __syncthreads();
    if (tid < MT){
      float v = psP[0][tid] + psP[1][tid] + psP[2][tid] + psP[3][tid] + lb[0];
      size_t row = (size_t)b*T + t0 + tid;
      if constexpr (MODE == 2){
        pred[row] = v;
        int lo2 = 0, hi2 = NBINS - 1;
        while (lo2 < hi2){ int mid = (lo2+hi2) >> 1;
                           if (bins[mid] < v) lo2 = mid + 1; else hi2 = mid; }
        idx[row] = lo2;
      } else {
        if (mask[row]) v = 0.f;
        logd[row] = v;
        float d = fmaxf(rintf(expf(v) - 1.f), 0.f);
        durf[row] = d;
        duri[row] = (int)d;
      }
    }
  }
}

// ---------------- per-batch inclusive cumsum of dur, mel_len ----------------
__global__ __launch_bounds__(1024) void cumsum_kernel(const int* __restrict__ duri,
    int* __restrict__ cum, float* __restrict__ mel, int T, int ML)
{
  __shared__ int s[1024];
  int b = blockIdx.x, tid = threadIdx.x;
  s[tid] = (tid < T) ? duri[(size_t)b*T + tid] : 0;
  __syncthreads();
  for (int off = 1; off < 1024; off <<= 1){
    int add = (tid >= off) ? s[tid-off] : 0;
    __syncthreads();
    s[tid] += add;
    __syncthreads();
  }
  if (tid < T) cum[(size_t)b*T + tid] = s[tid];
  if (tid == T-1) mel[b] = (float)min(s[tid], ML);
}

// ------- length regulate, fused x_adapt: out[f] = x[s]+pt[ip[s]]+et[ie[s]] ---
__global__ __launch_bounds__(256) void lr_kernel(const float* __restrict__ x,
    const int* __restrict__ ip, const int* __restrict__ ie,
    const float* __restrict__ pt, const float* __restrict__ et,
    const int* __restrict__ cum, float* __restrict__ out, int T, int ML)
{
  constexpr int FR = 32;
  __shared__ int scum[1024];
  __shared__ int sidx[FR];
  __shared__ int svalid[FR];
  __shared__ int sip[FR], sie[FR];
  int b  = blockIdx.y;
  int f0 = blockIdx.x * FR;
  for (int i = threadIdx.x; i < T; i += 256) scum[i] = cum[(size_t)b*T + i];
  __syncthreads();
  int total = scum[T-1];
  if (threadIdx.x < FR){
    int f = f0 + threadIdx.x;
    int lo = 0, hi = T;
    while (lo < hi){ int mid = (lo + hi) >> 1; if (scum[mid] <= f) lo = mid + 1; else hi = mid; }
    int s = min(lo, T-1);
    sidx[threadIdx.x] = s;
    svalid[threadIdx.x] = (f < total) ? 1 : 0;
    size_t grow = (size_t)b*T + s;
    sip[threadIdx.x] = ip[grow];
    sie[threadIdx.x] = ie[grow];
  }
  __syncthreads();
  #pragma unroll
  for (int it = 0; it < FR*(HH/4)/256; ++it){
    int item = it*256 + threadIdx.x;
    int fl = item / (HH/4);
    int c  = item - fl*(HH/4);
    int f  = f0 + fl;
    if (f >= ML) continue;
    float4 v = make_float4(0.f,0.f,0.f,0.f);
    if (svalid[fl]){
      float4 xv = ((const float4*)(x  + ((size_t)b*T + sidx[fl])*HH))[c];
      float4 pv = ((const float4*)(pt + (size_t)sip[fl]*HH))[c];
      float4 ev = ((const float4*)(et + (size_t)sie[fl]*HH))[c];
      v = make_float4(xv.x+pv.x+ev.x, xv.y+pv.y+ev.y,
                      xv.z+pv.z+ev.z, xv.w+pv.w+ev.w);
    }
    ((float4*)(out + ((size_t)b*ML + f)*HH))[c] = v;
  }
}

extern "C" void kernel_launch(void* const* d_in, const int* in_sizes, int n_in,
                              void* d_out, int out_size, void* d_ws, size_t ws_size,
                              hipStream_t stream)
{
  const float* x        = (const float*)d_in[0];
  const unsigned char* src_mask = (const unsigned char*)d_in[2];
  const float* dp_w1 = (const float*)d_in[4];
  const float* dp_b1 = (const float*)d_in[5];
  const float* dp_g1 = (const float*)d_in[6];
  const float* dp_be1= (const float*)d_in[7];
  const float* dp_w2 = (const float*)d_in[8];
  const float* dp_b2 = (const float*)d_in[9];
  const float* dp_g2 = (const float*)d_in[10];
  const float* dp_be2= (const float*)d_in[11];
  const float* dp_lw = (const float*)d_in[12];
  const float* dp_lb = (const float*)d_in[13];
  const float* pp_cw = (const float*)d_in[14];
  const float* pp_cb = (const float*)d_in[15];
  const float* pp_g  = (const float*)d_in[16];
  const float* pp_b  = (const float*)d_in[17];
  const float* pp_lw = (const float*)d_in[18];
  const float* pp_lb = (const float*)d_in[19];
  const float* pp_alpha = (const float*)d_in[20];
  const float* ep_cw = (const float*)d_in[21];
  const float* ep_cb = (const float*)d_in[22];
  const float* ep_g  = (const float*)d_in[23];
  const float* ep_b  = (const float*)d_in[24];
  const float* ep_lw = (const float*)d_in[25];
  const float* ep_lb = (const float*)d_in[26];
  const float* ep_alpha = (const float*)d_in[27];
  const float* pbins = (const float*)d_in[28];
  const float* ebins = (const float*)d_in[29];
  const float* ptab  = (const float*)d_in[30];
  const float* etab  = (const float*)d_in[31];

  int B = in_sizes[1];
  int T = in_sizes[0] / (B*HH);
  int ML = (int)(((long long)out_size - B - 4LL*B*T) / ((long long)B*HH));
  size_t rows = (size_t)B*T;

  float* bufA = (float*)d_ws;
  float* bufB = bufA + rows*HH;
  int* pos    = (int*)(bufB + rows*HH);
  int* idx_p  = pos + rows;
  int* idx_e  = idx_p + rows;
  int* dur_i  = idx_e + rows;
  int* cum    = dur_i + rows;

  float* out0    = (float*)d_out;
  float* logd    = out0 + (size_t)B*ML*HH;
  float* durf    = logd + rows;
  float* pitchp  = durf + rows;
  float* energyp = pitchp + rows;
  float* mel     = energyp + rows;

  // Transformed-weight scratch lives in the out0 gather region (201 MB);
  // lr_kernel fully overwrites it at the end of every call. ~25 MB used.
  const size_t SPL5 = (size_t)(24*5 + 2)*6144;  // shorts per split, k=5
  const size_t SPL3 = (size_t)(24*3 + 2)*6144;  // shorts per split, k=3
  unsigned short* wsc    = (unsigned short*)d_out;
  unsigned short* pitchW = wsc;
  unsigned short* enerW  = pitchW + 5*2*SPL5;
  unsigned short* durW1  = enerW  + 2*2*SPL5;
  unsigned short* durW2  = durW1  + 2*SPL3;

  const int per = 384*384;
  wtrans_kernel<5><<<(5*per + 255)/256, 256, 0, stream>>>(pp_cw, pitchW, 5);
  wtrans_kernel<5><<<(2*per + 255)/256, 256, 0, stream>>>(ep_cw, enerW, 2);
  wtrans_kernel<3><<<(per + 255)/256, 256, 0, stream>>>(dp_w1, durW1, 1);
  wtrans_kernel<3><<<(per + 255)/256, 256, 0, stream>>>(dp_w2, durW2, 1);

  int conv_grid = B * (T / 64);

  pos_kernel<<<B, 1024, 0, stream>>>(x, pos, T);

#define NOPX nullptr, nullptr
#define NOPROJ nullptr, nullptr, nullptr, nullptr, nullptr
#define NODUR  nullptr, nullptr, nullptr, nullptr

  // ---- pitch predictor: 5 conv layers (k=5); L1 fuses +PE, L5 fuses proj ----
  {
    unsigned short* w0 = pitchW;
    conv_mfma_kernel<5,1><<<conv_grid, 256, 0, stream>>>(x, w0, w0 + SPL5,
        pp_cb, pp_g, pp_b, bufB, T, pos, pp_alpha, NOPROJ, NODUR);
    float* src = bufB; float* dst = bufA;
    for (int l = 1; l < 4; ++l){
      unsigned short* whi = pitchW + (size_t)l*2*SPL5;
      conv_mfma_kernel<5,0><<<conv_grid, 256, 0, stream>>>(src, whi, whi + SPL5,
          pp_cb + (size_t)l*HH, pp_g + (size_t)l*HH, pp_b + (size_t)l*HH,
          dst, T, NOPX, NOPROJ, NODUR);
      float* t2 = dst; dst = src; src = t2;
    }
    unsigned short* w4 = pitchW + (size_t)4*2*SPL5;
    conv_mfma_kernel<5,2><<<conv_grid, 256, 0, stream>>>(src, w4, w4 + SPL5,
        pp_cb + (size_t)4*HH, pp_g + (size_t)4*HH, pp_b + (size_t)4*HH,
        nullptr, T, NOPX, pp_lw, pp_lb, pbins, pitchp, idx_p, NODUR);
  }

  // ---- energy predictor: 2 conv layers; L1 fuses +PE, L2 fuses proj ----
  {
    conv_mfma_kernel<5,1><<<conv_grid, 256, 0, stream>>>(x, enerW, enerW + SPL5,
        ep_cb, ep_g, ep_b, bufB, T, pos, ep_alpha, NOPROJ, NODUR);
    unsigned short* w1 = enerW + 2*SPL5;
    conv_mfma_kernel<5,2><<<conv_grid, 256, 0, stream>>>(bufB, w1, w1 + SPL5,
        ep_cb + (size_t)HH, ep_g + (size_t)HH, ep_b + (size_t)HH,
        nullptr, T, NOPX, ep_lw, ep_lb, ebins, energyp, idx_e, NODUR);
  }

  // ---- duration predictor: 2 conv layers (k=3); L2 fuses duration proj ----
  conv_mfma_kernel<3,0><<<conv_grid, 256, 0, stream>>>(x, durW1, durW1 + SPL3,
      dp_b1, dp_g1, dp_be1, bufB, T, NOPX, NOPROJ, NODUR);
  conv_mfma_kernel<3,3><<<conv_grid, 256, 0, stream>>>(bufB, durW2, durW2 + SPL3,
      dp_b2, dp_g2, dp_be2, nullptr, T, NOPX, dp_lw, dp_lb,
      nullptr, nullptr, nullptr, src_mask, logd, durf, dur_i);

#undef NOPX
#undef NOPROJ
#undef NODUR

  cumsum_kernel<<<B, 1024, 0, stream>>>(dur_i, cum, mel, T, ML);

  lr_kernel<<<dim3(ML/32, B), 256, 0, stream>>>(x, idx_p, idx_e, ptab, etab,
                                                cum, out0, T, ML);
}

// Round 15
// 1367.454 us; speedup vs baseline: 1.1665x; 1.0027x over previous
//
#include <hip/hip_runtime.h>
#include <cstdint>

#define HH 384
#define NBINS 256

typedef __attribute__((ext_vector_type(8))) short short8v;
typedef __attribute__((ext_vector_type(16))) float f32x16;
typedef __attribute__((ext_vector_type(4))) unsigned short ushort4v;

__device__ inline float4 ld4(const float* p){ return *(const float4*)p; }

__device__ inline unsigned short bf16_rne(float f){
  unsigned u = __float_as_uint(f);
  unsigned r = u + 0x7FFFu + ((u >> 16) & 1u);
  return (unsigned short)(r >> 16);
}
__device__ inline float bf16_to_f(unsigned short h){
  return __uint_as_float(((unsigned)h) << 16);
}

// ---------------- pos = cumsum(x[...,0]!=0) * mask ----------------
__global__ __launch_bounds__(1024) void pos_kernel(const float* __restrict__ x,
    int* __restrict__ pos, int T)
{
  __shared__ int s[1024];
  int b = blockIdx.x, tid = threadIdx.x;
  int m = 0;
  if (tid < T) m = (x[((size_t)b*T + tid)*HH] != 0.f) ? 1 : 0;
  s[tid] = m;
  __syncthreads();
  for (int off = 1; off < 1024; off <<= 1){
    int add = (tid >= off) ? s[tid-off] : 0;
    __syncthreads();
    s[tid] += add;
    __syncthreads();
  }
  if (tid < T) pos[(size_t)b*T + tid] = s[tid] * m;
}

// ---------------- weight transform: w[l][o][i][k] f32 -> B-frag bf16 hi/lo ---
// 32x32x16 B layout: lane l: col n = l&31, k-slot = (l>>5)*8 + j.
// PHASE-MAJOR K-order for K-chunked A staging: phase p = ch/192.
// step s = p*12*K + k*12 + ((ch%192)>>4); within step: half=(ch>>3)&1, jj=ch&7.
// Storage per layer: [hi | lo], each split [s][half(2)][o(384)][jj(8)],
// padded +2 steps so the conv pipeline may overrun harmlessly at the very end.
template<int K>
__global__ __launch_bounds__(256) void wtrans_kernel(const float* __restrict__ w,
    unsigned short* __restrict__ dst, int nlayers)
{
  constexpr int SPL = (24*K + 2) * 6144;   // shorts per split (padded)
  const int per = 384*384;
  int gid = blockIdx.x*256 + threadIdx.x;
  if (gid >= nlayers*per) return;
  int l = gid / per, rem = gid - l*per;
  int o = rem / 384, i = rem - (rem/384)*384;
  unsigned short* whi = dst + (size_t)l*2*SPL;
  unsigned short* wlo = whi + SPL;
  const float* wl = w + (size_t)l*384*384*K;
  int ph = (i >= 192) ? 1 : 0;
  int iloc = i - 192*ph;
  int c = iloc >> 4, half = (iloc >> 3) & 1, jj = iloc & 7;
  #pragma unroll
  for (int k = 0; k < K; ++k){
    float v = wl[((size_t)o*384 + i)*K + k];
    unsigned short hi = bf16_rne(v);
    unsigned short lo = bf16_rne(v - bf16_to_f(hi));
    int s = ph*12*K + k*12 + c;
    size_t d = ((size_t)(s*2 + half)*384 + o)*8 + jj;
    whi[d] = hi; wlo[d] = lo;
  }
}

// ---------------- fused conv1d(same,K)+relu+LN via bf16-split 32x32x16 MFMA --
// Conv main loop frozen at r12's best config (M=64, 4 waves, K-chunked A
// staging, counted vmcnt(6); ~935 TF raw = plain-HIP structural ceiling,
// r5-r13 probes of traffic/TLP/depth/schedule all null). Fusion MODEs:
//   MODE 0: plain conv (+write)
//   MODE 1: staging adds alpha*sinusoidal_pe(pos)  [replaces add_pe_kernel]
//   MODE 2: epilogue = proj + searchsorted, NO output write [replaces proj_var]
//   MODE 3: epilogue = proj + mask/exp/round (duration), NO write
// r15: mode-specific LDS arrays conditionally sized (MODE0 == r12 exactly);
// sinv bank-interleaved [q][48] so consecutive lanes read consecutive banks.
template<int K, int MODE>
__global__ __launch_bounds__(256) void conv_mfma_kernel(
    const float* __restrict__ in, const unsigned short* __restrict__ whi,
    const unsigned short* __restrict__ wlo, const float* __restrict__ bias,
    const float* __restrict__ g, const float* __restrict__ be,
    float* __restrict__ out, int T,
    const int* __restrict__ posp, const float* __restrict__ alpha,
    const float* __restrict__ lw, const float* __restrict__ lb,
    const float* __restrict__ bins, float* __restrict__ pred,
    int* __restrict__ idx,
    const unsigned char* __restrict__ mask, float* __restrict__ logd,
    float* __restrict__ durf, int* __restrict__ duri)
{
  constexpr int MT  = 64;
  constexpr int P   = (K-1)/2;
  constexpr int RT  = MT + K - 1;
  constexpr int RA  = RT + 2;        // +2 rows: prefetch overrun pad
  constexpr int SPH = 12*K;          // steps per phase (60 / 36)
  constexpr int LDPc = 200;          // 192 + 8 pad: 400B row stride
  __shared__ unsigned short xs_hi[RA*LDPc];
  __shared__ unsigned short xs_lo[RA*LDPc];
  __shared__ float ps[4][64], pq[4][64];
  __shared__ float psP[(MODE >= 2) ? 4*64 : 1];  // proj partials (MODE>=2)
  __shared__ float sinv[(MODE == 1) ? 192 : 1];  // inv-freq table, [q][48]

  int ntile = T / MT;
  int b  = blockIdx.x / ntile;
  int t0 = (blockIdx.x % ntile) * MT;
  int tid = threadIdx.x;
  const float* inb = in + (size_t)b*T*HH;

  int wv = tid >> 6, ln = tid & 63;
  int l31 = ln & 31, hl = ln >> 5;
  int o0 = wv * 96;

  float al = 0.f;
  if constexpr (MODE == 1){
    al = alpha[0];
    // interleaved: element i stored at sinv[(i&3)*48 + (i>>2)]
    if (tid < 192) sinv[(tid&3)*48 + (tid>>2)]
                     = expf((float)tid * -0.04822167734018944f);
    __syncthreads();
  }

  f32x16 acc0[3], acc1[3];
  #pragma unroll
  for (int nt = 0; nt < 3; ++nt){
    float bv = bias[o0 + nt*32 + l31];
    #pragma unroll
    for (int r = 0; r < 16; ++r){ acc0[nt][r] = bv; acc1[nt][r] = bv; }
  }

#define GLOAD(dst, p) \
  asm volatile("global_load_dwordx4 %0, %1, off" : "=v"(dst) : "v"(p))

  for (int phse = 0; phse < 2; ++phse){
    if (phse) __syncthreads();   // all waves done reading previous A phase

    // ---- stage channels [phse*192, phse*192+192) for RT rows, bf16 hi/lo ----
    for (int e4 = tid; e4 < RT*48; e4 += 256){
      int r = e4 / 48, c4 = (e4 - r*48)*4;
      int t = t0 + r - P;
      float4 v = (t >= 0 && t < T) ? ld4(&inb[(size_t)t*HH + phse*192 + c4])
                                   : make_float4(0.f,0.f,0.f,0.f);
      float va[4] = {v.x, v.y, v.z, v.w};
      if constexpr (MODE == 1){
        if (t >= 0 && t < T){
          int p = posp[(size_t)b*T + t];
          if (p){
            #pragma unroll
            for (int q = 0; q < 4; ++q){
              float ang = (float)p * sinv[q*48 + (c4 >> 2)];
              va[q] += al * (phse == 0 ? sinf(ang) : cosf(ang));
            }
          }
        }
      }
      ushort4v h, l;
      #pragma unroll
      for (int q = 0; q < 4; ++q){
        unsigned short hq = bf16_rne(va[q]);
        h[q] = hq;
        l[q] = bf16_rne(va[q] - bf16_to_f(hq));
      }
      *(ushort4v*)&xs_hi[r*LDPc + c4] = h;
      *(ushort4v*)&xs_lo[r*LDPc + c4] = l;
    }
    __syncthreads();

    const unsigned short* bhp = whi + (size_t)phse*SPH*6144
                                    + ((size_t)hl*384 + o0 + l31)*8;
    const unsigned short* blp = wlo + (size_t)phse*SPH*6144
                                    + ((size_t)hl*384 + o0 + l31)*8;
    int aoff0 = l31*LDPc + hl*8;          // row-group 0: rows 0..31
    int aoff1 = (32 + l31)*LDPc + hl*8;   // row-group 1: rows 32..63
    int cc = 0;

    short8v B0h[3], B0l[3], B1h[3], B1l[3];
    short8v A00h, A00l, A01h, A01l;   // A set 0: rg0, rg1
    short8v A10h, A10l, A11h, A11l;   // A set 1

#define ADVB do{ bhp += 6144; blp += 6144; }while(0)
#define ADVA do{ aoff0 += 16; aoff1 += 16;                                   \
                 if (++cc == 12){ cc = 0; aoff0 += LDPc - 192;               \
                                  aoff1 += LDPc - 192; } }while(0)

    // prologue: B set 0 <- step 0 (6 loads in flight); A set 0 <- step 0
    GLOAD(B0h[0], bhp);        GLOAD(B0h[1], bhp + 256); GLOAD(B0h[2], bhp + 512);
    GLOAD(B0l[0], blp);        GLOAD(B0l[1], blp + 256); GLOAD(B0l[2], blp + 512);
    ADVB;
    A00h = *(const short8v*)&xs_hi[aoff0];
    A00l = *(const short8v*)&xs_lo[aoff0];
    A01h = *(const short8v*)&xs_hi[aoff1];
    A01l = *(const short8v*)&xs_lo[aoff1];
    ADVA;

#define STEP(CBh,CBl, CA0h,CA0l,CA1h,CA1l, NBh,NBl, NA0h,NA0l,NA1h,NA1l) do{ \
    GLOAD(NBh[0], bhp);       GLOAD(NBh[1], bhp + 256);                      \
    GLOAD(NBh[2], bhp + 512); GLOAD(NBl[0], blp);                            \
    GLOAD(NBl[1], blp + 256); GLOAD(NBl[2], blp + 512);                      \
    ADVB;                                                                    \
    NA0h = *(const short8v*)&xs_hi[aoff0];                                   \
    NA0l = *(const short8v*)&xs_lo[aoff0];                                   \
    NA1h = *(const short8v*)&xs_hi[aoff1];                                   \
    NA1l = *(const short8v*)&xs_lo[aoff1];                                   \
    ADVA;                                                                    \
    asm volatile("s_waitcnt vmcnt(6)");                                      \
    __builtin_amdgcn_sched_barrier(0);                                       \
    __builtin_amdgcn_s_setprio(1);                                           \
    _Pragma("unroll")                                                        \
    for (int nt = 0; nt < 3; ++nt){                                          \
      acc0[nt] = __builtin_amdgcn_mfma_f32_32x32x16_bf16(CA0h, CBh[nt], acc0[nt], 0,0,0); \
      acc1[nt] = __builtin_amdgcn_mfma_f32_32x32x16_bf16(CA1h, CBh[nt], acc1[nt], 0,0,0); \
    }                                                                        \
    _Pragma("unroll")                                                        \
    for (int nt = 0; nt < 3; ++nt){                                          \
      acc0[nt] = __builtin_amdgcn_mfma_f32_32x32x16_bf16(CA0h, CBl[nt], acc0[nt], 0,0,0); \
      acc1[nt] = __builtin_amdgcn_mfma_f32_32x32x16_bf16(CA1h, CBl[nt], acc1[nt], 0,0,0); \
    }                                                                        \
    _Pragma("unroll")                                                        \
    for (int nt = 0; nt < 3; ++nt){                                          \
      acc0[nt] = __builtin_amdgcn_mfma_f32_32x32x16_bf16(CA0l, CBh[nt], acc0[nt], 0,0,0); \
      acc1[nt] = __builtin_amdgcn_mfma_f32_32x32x16_bf16(CA1l, CBh[nt], acc1[nt], 0,0,0); \
    }                                                                        \
    __builtin_amdgcn_s_setprio(0);                                           \
  } while(0)

    for (int s = 0; s < SPH; s += 2){
      STEP(B0h,B0l, A00h,A00l,A01h,A01l, B1h,B1l, A10h,A10l,A11h,A11l);
      STEP(B1h,B1l, A10h,A10l,A11h,A11l, B0h,B0l, A00h,A00l,A01h,A01l);
    }
#undef STEP
#undef ADVB
#undef ADVA

    // drain the (dead, pad-targeted) in-flight loads before barrier/epilogue
    asm volatile("s_waitcnt vmcnt(0)");
    __builtin_amdgcn_sched_barrier(0);
  }
#undef GLOAD

  // ---- relu + LN stats over channels ----
  // D layout (32x32): col o = o0+nt*32+l31; local row = (r&3)+8*(r>>2)+4*hl
  float gv[3], bev[3];
  #pragma unroll
  for (int nt = 0; nt < 3; ++nt){
    gv[nt]  = g[o0 + nt*32 + l31];
    bev[nt] = be[o0 + nt*32 + l31];
  }

  #pragma unroll
  for (int rg = 0; rg < 2; ++rg){
    #pragma unroll
    for (int r = 0; r < 16; ++r){
      float s1 = 0.f, s2 = 0.f;
      #pragma unroll
      for (int nt = 0; nt < 3; ++nt){
        float v = fmaxf(rg ? acc1[nt][r] : acc0[nt][r], 0.f);
        if (rg) acc1[nt][r] = v; else acc0[nt][r] = v;
        s1 += v; s2 += v*v;
      }
      s1 += __shfl_xor(s1, 1);  s2 += __shfl_xor(s2, 1);
      s1 += __shfl_xor(s1, 2);  s2 += __shfl_xor(s2, 2);
      s1 += __shfl_xor(s1, 4);  s2 += __shfl_xor(s2, 4);
      s1 += __shfl_xor(s1, 8);  s2 += __shfl_xor(s2, 8);
      s1 += __shfl_xor(s1, 16); s2 += __shfl_xor(s2, 16);
      if (l31 == 0){
        int t = rg*32 + (r&3) + 8*(r>>2) + 4*hl;
        ps[wv][t] = s1; pq[wv][t] = s2;
      }
    }
  }
  __syncthreads();

  if constexpr (MODE <= 1){
    #pragma unroll
    for (int rg = 0; rg < 2; ++rg){
      #pragma unroll
      for (int r = 0; r < 16; ++r){
        int t = rg*32 + (r&3) + 8*(r>>2) + 4*hl;
        float s1 = ps[0][t] + ps[1][t] + ps[2][t] + ps[3][t];
        float s2 = pq[0][t] + pq[1][t] + pq[2][t] + pq[3][t];
        float mn  = s1 * (1.f/HH);
        float var = fmaxf(s2 * (1.f/HH) - mn*mn, 0.f);
        float rr  = rsqrtf(var + 1e-5f);
        float* orow = out + ((size_t)b*T + t0 + t)*HH;
        #pragma unroll
        for (int nt = 0; nt < 3; ++nt){
          float v = rg ? acc1[nt][r] : acc0[nt][r];
          orow[o0 + nt*32 + l31] = (v - mn)*rr*gv[nt] + bev[nt];
        }
      }
    }
  } else {
    // ---- fused projection epilogue (no output write) ----
    float lwv[3];
    #pragma unroll
    for (int nt = 0; nt < 3; ++nt) lwv[nt] = lw[o0 + nt*32 + l31];
    #pragma unroll
    for (int rg = 0; rg < 2; ++rg){
      #pragma unroll
      for (int r = 0; r < 16; ++r){
        int t = rg*32 + (r&3) + 8*(r>>2) + 4*hl;
        float s1 = ps[0][t] + ps[1][t] + ps[2][t] + ps[3][t];
        float s2 = pq[0][t] + pq[1][t] + pq[2][t] + pq[3][t];
        float mn  = s1 * (1.f/HH);
        float var = fmaxf(s2 * (1.f/HH) - mn*mn, 0.f);
        float rr  = rsqrtf(var + 1e-5f);
        float pv = 0.f;
        #pragma unroll
        for (int nt = 0; nt < 3; ++nt){
          float v = rg ? acc1[nt][r] : acc0[nt][r];
          pv += ((v - mn)*rr*gv[nt] + bev[nt]) * lwv[nt];
        }
        pv += __shfl_xor(pv, 1);  pv += __shfl_xor(pv, 2);
        pv += __shfl_xor(pv, 4);  pv += __shfl_xor(pv, 8);
        pv += __shfl_xor(pv, 16);
        if (l31 == 0) psP[wv*64 + t] = pv;
      }
    }
    __syncthreads();
    if (tid < MT){
      float v = psP[0*64 + tid] + psP[1*64 + tid]
              + psP[2*64 + tid] + psP[3*64 + tid] + lb[0];
      size_t row = (size_t)b*T + t0 + tid;
      if constexpr (MODE == 2){
        pred[row] = v;
        int lo2 = 0, hi2 = NBINS - 1;
        while (lo2 < hi2){ int mid = (lo2+hi2) >> 1;
                           if (bins[mid] < v) lo2 = mid + 1; else hi2 = mid; }
        idx[row] = lo2;
      } else {
        if (mask[row]) v = 0.f;
        logd[row] = v;
        float d = fmaxf(rintf(expf(v) - 1.f), 0.f);
        durf[row] = d;
        duri[row] = (int)d;
      }
    }
  }
}

// ---------------- per-batch inclusive cumsum of dur, mel_len ----------------
__global__ __launch_bounds__(1024) void cumsum_kernel(const int* __restrict__ duri,
    int* __restrict__ cum, float* __restrict__ mel, int T, int ML)
{
  __shared__ int s[1024];
  int b = blockIdx.x, tid = threadIdx.x;
  s[tid] = (tid < T) ? duri[(size_t)b*T + tid] : 0;
  __syncthreads();
  for (int off = 1; off < 1024; off <<= 1){
    int add = (tid >= off) ? s[tid-off] : 0;
    __syncthreads();
    s[tid] += add;
    __syncthreads();
  }
  if (tid < T) cum[(size_t)b*T + tid] = s[tid];
  if (tid == T-1) mel[b] = (float)min(s[tid], ML);
}

// ------- length regulate, fused x_adapt: out[f] = x[s]+pt[ip[s]]+et[ie[s]] ---
__global__ __launch_bounds__(256) void lr_kernel(const float* __restrict__ x,
    const int* __restrict__ ip, const int* __restrict__ ie,
    const float* __restrict__ pt, const float* __restrict__ et,
    const int* __restrict__ cum, float* __restrict__ out, int T, int ML)
{
  constexpr int FR = 32;
  __shared__ int scum[1024];
  __shared__ int sidx[FR];
  __shared__ int svalid[FR];
  __shared__ int sip[FR], sie[FR];
  int b  = blockIdx.y;
  int f0 = blockIdx.x * FR;
  for (int i = threadIdx.x; i < T; i += 256) scum[i] = cum[(size_t)b*T + i];
  __syncthreads();
  int total = scum[T-1];
  if (threadIdx.x < FR){
    int f = f0 + threadIdx.x;
    int lo = 0, hi = T;
    while (lo < hi){ int mid = (lo + hi) >> 1; if (scum[mid] <= f) lo = mid + 1; else hi = mid; }
    int s = min(lo, T-1);
    sidx[threadIdx.x] = s;
    svalid[threadIdx.x] = (f < total) ? 1 : 0;
    size_t grow = (size_t)b*T + s;
    sip[threadIdx.x] = ip[grow];
    sie[threadIdx.x] = ie[grow];
  }
  __syncthreads();
  #pragma unroll
  for (int it = 0; it < FR*(HH/4)/256; ++it){
    int item = it*256 + threadIdx.x;
    int fl = item / (HH/4);
    int c  = item - fl*(HH/4);
    int f  = f0 + fl;
    if (f >= ML) continue;
    float4 v = make_float4(0.f,0.f,0.f,0.f);
    if (svalid[fl]){
      float4 xv = ((const float4*)(x  + ((size_t)b*T + sidx[fl])*HH))[c];
      float4 pv = ((const float4*)(pt + (size_t)sip[fl]*HH))[c];
      float4 ev = ((const float4*)(et + (size_t)sie[fl]*HH))[c];
      v = make_float4(xv.x+pv.x+ev.x, xv.y+pv.y+ev.y,
                      xv.z+pv.z+ev.z, xv.w+pv.w+ev.w);
    }
    ((float4*)(out + ((size_t)b*ML + f)*HH))[c] = v;
  }
}

extern "C" void kernel_launch(void* const* d_in, const int* in_sizes, int n_in,
                              void* d_out, int out_size, void* d_ws, size_t ws_size,
                              hipStream_t stream)
{
  const float* x        = (const float*)d_in[0];
  const unsigned char* src_mask = (const unsigned char*)d_in[2];
  const float* dp_w1 = (const float*)d_in[4];
  const float* dp_b1 = (const float*)d_in[5];
  const float* dp_g1 = (const float*)d_in[6];
  const float* dp_be1= (const float*)d_in[7];
  const float* dp_w2 = (const float*)d_in[8];
  const float* dp_b2 = (const float*)d_in[9];
  const float* dp_g2 = (const float*)d_in[10];
  const float* dp_be2= (const float*)d_in[11];
  const float* dp_lw = (const float*)d_in[12];
  const float* dp_lb = (const float*)d_in[13];
  const float* pp_cw = (const float*)d_in[14];
  const float* pp_cb = (const float*)d_in[15];
  const float* pp_g  = (const float*)d_in[16];
  const float* pp_b  = (const float*)d_in[17];
  const float* pp_lw = (const float*)d_in[18];
  const float* pp_lb = (const float*)d_in[19];
  const float* pp_alpha = (const float*)d_in[20];
  const float* ep_cw = (const float*)d_in[21];
  const float* ep_cb = (const float*)d_in[22];
  const float* ep_g  = (const float*)d_in[23];
  const float* ep_b  = (const float*)d_in[24];
  const float* ep_lw = (const float*)d_in[25];
  const float* ep_lb = (const float*)d_in[26];
  const float* ep_alpha = (const float*)d_in[27];
  const float* pbins = (const float*)d_in[28];
  const float* ebins = (const float*)d_in[29];
  const float* ptab  = (const float*)d_in[30];
  const float* etab  = (const float*)d_in[31];

  int B = in_sizes[1];
  int T = in_sizes[0] / (B*HH);
  int ML = (int)(((long long)out_size - B - 4LL*B*T) / ((long long)B*HH));
  size_t rows = (size_t)B*T;

  float* bufA = (float*)d_ws;
  float* bufB = bufA + rows*HH;
  int* pos    = (int*)(bufB + rows*HH);
  int* idx_p  = pos + rows;
  int* idx_e  = idx_p + rows;
  int* dur_i  = idx_e + rows;
  int* cum    = dur_i + rows;

  float* out0    = (float*)d_out;
  float* logd    = out0 + (size_t)B*ML*HH;
  float* durf    = logd + rows;
  float* pitchp  = durf + rows;
  float* energyp = pitchp + rows;
  float* mel     = energyp + rows;

  // Transformed-weight scratch lives in the out0 gather region (201 MB);
  // lr_kernel fully overwrites it at the end of every call. ~25 MB used.
  const size_t SPL5 = (size_t)(24*5 + 2)*6144;  // shorts per split, k=5
  const size_t SPL3 = (size_t)(24*3 + 2)*6144;  // shorts per split, k=3
  unsigned short* wsc    = (unsigned short*)d_out;
  unsigned short* pitchW = wsc;
  unsigned short* enerW  = pitchW + 5*2*SPL5;
  unsigned short* durW1  = enerW  + 2*2*SPL5;
  unsigned short* durW2  = durW1  + 2*SPL3;

  const int per = 384*384;
  wtrans_kernel<5><<<(5*per + 255)/256, 256, 0, stream>>>(pp_cw, pitchW, 5);
  wtrans_kernel<5><<<(2*per + 255)/256, 256, 0, stream>>>(ep_cw, enerW, 2);
  wtrans_kernel<3><<<(per + 255)/256, 256, 0, stream>>>(dp_w1, durW1, 1);
  wtrans_kernel<3><<<(per + 255)/256, 256, 0, stream>>>(dp_w2, durW2, 1);

  int conv_grid = B * (T / 64);

  pos_kernel<<<B, 1024, 0, stream>>>(x, pos, T);

#define NOPX nullptr, nullptr
#define NOPROJ nullptr, nullptr, nullptr, nullptr, nullptr
#define NODUR  nullptr, nullptr, nullptr, nullptr

  // ---- pitch predictor: 5 conv layers (k=5); L1 fuses +PE, L5 fuses proj ----
  {
    unsigned short* w0 = pitchW;
    conv_mfma_kernel<5,1><<<conv_grid, 256, 0, stream>>>(x, w0, w0 + SPL5,
        pp_cb, pp_g, pp_b, bufB, T, pos, pp_alpha, NOPROJ, NODUR);
    float* src = bufB; float* dst = bufA;
    for (int l = 1; l < 4; ++l){
      unsigned short* whi = pitchW + (size_t)l*2*SPL5;
      conv_mfma_kernel<5,0><<<conv_grid, 256, 0, stream>>>(src, whi, whi + SPL5,
          pp_cb + (size_t)l*HH, pp_g + (size_t)l*HH, pp_b + (size_t)l*HH,
          dst, T, NOPX, NOPROJ, NODUR);
      float* t2 = dst; dst = src; src = t2;
    }
    unsigned short* w4 = pitchW + (size_t)4*2*SPL5;
    conv_mfma_kernel<5,2><<<conv_grid, 256, 0, stream>>>(src, w4, w4 + SPL5,
        pp_cb + (size_t)4*HH, pp_g + (size_t)4*HH, pp_b + (size_t)4*HH,
        nullptr, T, NOPX, pp_lw, pp_lb, pbins, pitchp, idx_p, NODUR);
  }

  // ---- energy predictor: 2 conv layers; L1 fuses +PE, L2 fuses proj ----
  {
    conv_mfma_kernel<5,1><<<conv_grid, 256, 0, stream>>>(x, enerW, enerW + SPL5,
        ep_cb, ep_g, ep_b, bufB, T, pos, ep_alpha, NOPROJ, NODUR);
    unsigned short* w1 = enerW + 2*SPL5;
    conv_mfma_kernel<5,2><<<conv_grid, 256, 0, stream>>>(bufB, w1, w1 + SPL5,
        ep_cb + (size_t)HH, ep_g + (size_t)HH, ep_b + (size_t)HH,
        nullptr, T, NOPX, ep_lw, ep_lb, ebins, energyp, idx_e, NODUR);
  }

  // ---- duration predictor: 2 conv layers (k=3); L2 fuses duration proj ----
  conv_mfma_kernel<3,0><<<conv_grid, 256, 0, stream>>>(x, durW1, durW1 + SPL3,
      dp_b1, dp_g1, dp_be1, bufB, T, NOPX, NOPROJ, NODUR);
  conv_mfma_kernel<3,3><<<conv_grid, 256, 0, stream>>>(bufB, durW2, durW2 + SPL3,
      dp_b2, dp_g2, dp_be2, nullptr, T, NOPX, dp_lw, dp_lb,
      nullptr, nullptr, nullptr, src_mask, logd, durf, dur_i);

#undef NOPX
#undef NOPROJ
#undef NODUR

  cumsum_kernel<<<B, 1024, 0, stream>>>(dur_i, cum, mel, T, ML);

  lr_kernel<<<dim3(ML/32, B), 256, 0, stream>>>(x, idx_p, idx_e, ptab, etab,
                                                cum, out0, T, ML);
}